// Round 4
// baseline (436.144 us; speedup 1.0000x reference)
//
#include <hip/hip_runtime.h>

typedef _Float16 f16;
typedef _Float16 f16x8 __attribute__((ext_vector_type(8)));
typedef float f32x4 __attribute__((ext_vector_type(4)));

#define B_   4
#define C_   256
#define N_   4096
#define OUT_ 256

// ---------------------------------------------------------------------------
// Kernel A: transpose+convert x [B,C,N] f32 -> xt [B,N,C] f16, W -> Wt[o][c] f16,
// and zero the BN-stats accumulators (block 1088).
// ---------------------------------------------------------------------------
__global__ __launch_bounds__(256) void k_prep(const float* __restrict__ x,
                                              const float* __restrict__ W,
                                              f16* __restrict__ xt,
                                              f16* __restrict__ Wt,
                                              float* __restrict__ stats) {
    int bid = blockIdx.x;
    int t = threadIdx.x;
    if (bid < 1024) {
        int b  = bid >> 8;
        int ct = (bid >> 6) & 3;
        int nt = bid & 63;
        int c0 = ct * 64, n0 = nt * 64;
        __shared__ float tile[64][65];
        int nl = t & 63;
        int r0 = t >> 6;
        #pragma unroll
        for (int i = 0; i < 16; ++i) {
            int cl = i * 4 + r0;
            tile[cl][nl] = x[((b * C_ + c0 + cl) * N_) + n0 + nl];
        }
        __syncthreads();
        #pragma unroll
        for (int i = 0; i < 16; ++i) {
            int nl2 = i * 4 + r0;
            int cl2 = nl;
            xt[((b * N_ + n0 + nl2) * C_) + c0 + cl2] = (f16)tile[cl2][nl2];
        }
    } else if (bid < 1088) {
        int wb = bid - 1024;
        #pragma unroll
        for (int i = 0; i < 4; ++i) {
            int idx = wb * 1024 + i * 256 + t;
            int c = idx >> 8, o = idx & 255;
            Wt[o * C_ + c] = (f16)W[idx];
        }
    } else {
        if (t < 512) stats[t] = 0.f;
    }
}

// ---------------------------------------------------------------------------
// Kernel B: support^T[b][o][m] = sum_c xt[b][m][c] * W[c][o]   (f16 out)
// ---------------------------------------------------------------------------
__global__ __launch_bounds__(256) void k_support(const f16* __restrict__ xt,
                                                 const f16* __restrict__ Wt,
                                                 f16* __restrict__ supT) {
    int bid = blockIdx.x;
    int b  = bid >> 8;
    int ot = (bid >> 6) & 3;
    int mt = bid & 63;
    int o0 = ot * 64, m0 = mt * 64;
    __shared__ __align__(16) f16 Ws[64][264];
    __shared__ __align__(16) f16 Xs[64][264];
    int t = threadIdx.x;
    int wave = t >> 6, lane = t & 63, q = lane >> 4, l15 = lane & 15;
    #pragma unroll
    for (int p = 0; p < 8; ++p) {
        int idx = p * 256 + t;
        int row = idx >> 5, ch = (idx & 31) * 8;
        *(uint4*)&Ws[row][ch] = *(const uint4*)&Wt[(o0 + row) * C_ + ch];
        *(uint4*)&Xs[row][ch] = *(const uint4*)&xt[((b * N_) + m0 + row) * C_ + ch];
    }
    __syncthreads();
    f32x4 acc[4] = {};
    #pragma unroll
    for (int kk = 0; kk < 8; ++kk) {
        f16x8 a = *(f16x8*)&Ws[16 * wave + l15][kk * 32 + q * 8];
        #pragma unroll
        for (int ct = 0; ct < 4; ++ct) {
            f16x8 bb = *(f16x8*)&Xs[16 * ct + l15][kk * 32 + q * 8];
            acc[ct] = __builtin_amdgcn_mfma_f32_16x16x32_f16(a, bb, acc[ct], 0, 0, 0);
        }
    }
    #pragma unroll
    for (int ct = 0; ct < 4; ++ct)
        #pragma unroll
        for (int r = 0; r < 4; ++r) {
            int og = o0 + 16 * wave + q * 4 + r;
            int mg = m0 + 16 * ct + l15;
            supT[((b * OUT_ + og) * N_) + mg] = (f16)acc[ct][r];
        }
}

// ---------------------------------------------------------------------------
// Kernel C: split-K(2) flash, K/V fragments DIRECT FROM GLOBAL (L2-resident),
// LDS only for the P layout transform. grid 512: bid = h*256 + b*64 + nb.
// BM=64 (Q in regs), BN=64, 32 iters over m-range [h*2048,(h+1)*2048).
// ---------------------------------------------------------------------------
__global__ __launch_bounds__(256, 2) void k_flash(const f16* __restrict__ xt,
                                                  const f16* __restrict__ supT,
                                                  f16* __restrict__ Op,
                                                  float* __restrict__ Ml) {
    int bid = blockIdx.x;
    int h  = bid >> 8;
    int b  = (bid >> 6) & 3;
    int n0 = (bid & 63) * 64;

    __shared__ __align__(16) f16 Ps[64][72];    // 9216 B
    __shared__ __align__(16) float Al[64];      //  256 B

    int t = threadIdx.x;
    int wave = t >> 6, lane = t & 63, q = lane >> 4, l15 = lane & 15;

    // Q fragments: rows 16*wave + l15, 256 channels -> 8 f16x8 (32 VGPRs)
    const f16* qbase = xt + ((size_t)(b * N_) + n0 + 16 * wave + l15) * C_;
    f16x8 qf[8];
    #pragma unroll
    for (int kk = 0; kk < 8; ++kk)
        qf[kk] = *(const f16x8*)&qbase[kk * 32 + q * 8];

    // per-lane gather bases: K rows (l15), V rows (o = 64*wave + 16*ot + l15)
    const f16* kb0 = xt + ((size_t)(b * N_) + l15) * C_ + q * 8;        // + m-row*C_ + ct*16*C_ + kk*32
    const f16* vb0 = supT + ((size_t)(b * OUT_) + 64 * wave + l15) * N_ + q * 8;  // + ot*16*N_ + m0 + ks*32

    f32x4 oacc[4][4] = {};
    float m_run[4], l_run[4];
    #pragma unroll
    for (int r = 0; r < 4; ++r) { m_run[r] = -1e30f; l_run[r] = 0.f; }

    for (int it = 0; it < 32; ++it) {
        int m0 = h * 2048 + it * 64;
        // --- S = Q K^T (64x64, K=256); wave owns rows 16*wave..+15
        const f16* kb = kb0 + (size_t)m0 * C_;
        f32x4 sacc[4] = {};
        #pragma unroll
        for (int kk = 0; kk < 8; ++kk) {
            f16x8 kf[4];
            #pragma unroll
            for (int ct = 0; ct < 4; ++ct)
                kf[ct] = *(const f16x8*)&kb[(size_t)ct * 16 * C_ + kk * 32];
            #pragma unroll
            for (int ct = 0; ct < 4; ++ct)
                sacc[ct] = __builtin_amdgcn_mfma_f32_16x16x32_f16(qf[kk], kf[ct], sacc[ct], 0, 0, 0);
        }
        // --- online softmax; publish P (f16) and alpha
        float alpha[4];
        #pragma unroll
        for (int r = 0; r < 4; ++r) {
            float mx = fmaxf(fmaxf(sacc[0][r], sacc[1][r]), fmaxf(sacc[2][r], sacc[3][r]));
            mx = fmaxf(mx, __shfl_xor(mx, 1));
            mx = fmaxf(mx, __shfl_xor(mx, 2));
            mx = fmaxf(mx, __shfl_xor(mx, 4));
            mx = fmaxf(mx, __shfl_xor(mx, 8));
            float mnew = fmaxf(m_run[r], mx);
            alpha[r] = __expf(m_run[r] - mnew);
            m_run[r] = mnew;
            float p0 = __expf(sacc[0][r] - mnew);
            float p1 = __expf(sacc[1][r] - mnew);
            float p2 = __expf(sacc[2][r] - mnew);
            float p3 = __expf(sacc[3][r] - mnew);
            float sum = p0 + p1 + p2 + p3;
            sum += __shfl_xor(sum, 1);
            sum += __shfl_xor(sum, 2);
            sum += __shfl_xor(sum, 4);
            sum += __shfl_xor(sum, 8);
            l_run[r] = l_run[r] * alpha[r] + sum;
            int row = 16 * wave + q * 4 + r;
            Ps[row][0 * 16 + l15] = (f16)p0;
            Ps[row][1 * 16 + l15] = (f16)p1;
            Ps[row][2 * 16 + l15] = (f16)p2;
            Ps[row][3 * 16 + l15] = (f16)p3;
            if (l15 == 0) Al[row] = alpha[r];
        }
        __syncthreads();

        // --- rescale O by alpha (broadcast via LDS), then O += P V
        // wave computes O[all 64 n][o-slab 64*wave .. +64)
        float4 av[4];
        #pragma unroll
        for (int nt = 0; nt < 4; ++nt)
            av[nt] = *(const float4*)&Al[16 * nt + 4 * q];
        #pragma unroll
        for (int nt = 0; nt < 4; ++nt)
            #pragma unroll
            for (int ot = 0; ot < 4; ++ot)
                #pragma unroll
                for (int r = 0; r < 4; ++r)
                    oacc[nt][ot][r] *= ((const float*)&av[nt])[r];
        const f16* vb = vb0 + m0;
        #pragma unroll
        for (int ks = 0; ks < 2; ++ks) {
            f16x8 af[4], bf[4];
            #pragma unroll
            for (int ot = 0; ot < 4; ++ot)
                bf[ot] = *(const f16x8*)&vb[(size_t)ot * 16 * N_ + ks * 32];
            #pragma unroll
            for (int nt = 0; nt < 4; ++nt)
                af[nt] = *(f16x8*)&Ps[16 * nt + l15][ks * 32 + q * 8];
            #pragma unroll
            for (int nt = 0; nt < 4; ++nt)
                #pragma unroll
                for (int ot = 0; ot < 4; ++ot)
                    oacc[nt][ot] = __builtin_amdgcn_mfma_f32_16x16x32_f16(af[nt], bf[ot], oacc[nt][ot], 0, 0, 0);
        }
        __syncthreads();
    }

    // store l-normalized f16 partials + (m,l)
    if (l15 == 0) {
        #pragma unroll
        for (int r = 0; r < 4; ++r)
            Al[16 * wave + q * 4 + r] = 1.0f / l_run[r];
    }
    __syncthreads();
    float4 lv[4];
    #pragma unroll
    for (int nt = 0; nt < 4; ++nt)
        lv[nt] = *(const float4*)&Al[16 * nt + 4 * q];

    f16* Obase = Op + (size_t)bid * (64 * 256);
    #pragma unroll
    for (int nt = 0; nt < 4; ++nt)
        #pragma unroll
        for (int ot = 0; ot < 4; ++ot)
            #pragma unroll
            for (int r = 0; r < 4; ++r) {
                int n = 16 * nt + q * 4 + r;
                int o = 64 * wave + 16 * ot + l15;
                Obase[n * 256 + o] = (f16)(oacc[nt][ot][r] * ((const float*)&lv[nt])[r]);
            }
    float* Mlb = Ml + (size_t)bid * 128;
    if (l15 == 0) {
        #pragma unroll
        for (int r = 0; r < 4; ++r) {
            Mlb[16 * wave + q * 4 + r] = m_run[r];
            Mlb[64 + 16 * wave + q * 4 + r] = l_run[r];
        }
    }
}

// ---------------------------------------------------------------------------
// Kernel C2: merge 2 split-K halves + LeakyReLU -> y (f16, [b][o][n]),
// and accumulate per-channel BN sums via atomics.
// grid 256 = (b, nb); thread t owns output channel o = t.
// ---------------------------------------------------------------------------
__global__ __launch_bounds__(256) void k_merge(const f16* __restrict__ Op,
                                               const float* __restrict__ Ml,
                                               f16* __restrict__ y,
                                               float* __restrict__ stats) {
    int bid = blockIdx.x;
    int b  = bid >> 6;
    int nb = bid & 63;
    int t = threadIdx.x;
    const f16* O0 = Op + (size_t)bid * (64 * 256);
    const f16* O1 = Op + (size_t)(bid + 256) * (64 * 256);
    __shared__ float cs[2][64];
    if (t < 64) {
        const float* M0 = Ml + (size_t)bid * 128;
        const float* M1 = Ml + (size_t)(bid + 256) * 128;
        float m0 = M0[t], l0 = M0[64 + t];
        float m1 = M1[t], l1 = M1[64 + t];
        float M = fmaxf(m0, m1);
        float w0 = __expf(m0 - M) * l0;
        float w1 = __expf(m1 - M) * l1;
        float inv = 1.0f / (w0 + w1);
        cs[0][t] = w0 * inv;
        cs[1][t] = w1 * inv;
    }
    __syncthreads();
    float vv[64];
    float s = 0.f, ss = 0.f;
    #pragma unroll
    for (int n = 0; n < 64; ++n) {
        float v = cs[0][n] * (float)O0[n * 256 + t] + cs[1][n] * (float)O1[n * 256 + t];
        v = v >= 0.f ? v : 0.01f * v;
        vv[n] = v;
        s += v;
        ss += v * v;
    }
    f16* dst = y + ((size_t)(b * OUT_ + t)) * N_ + nb * 64;
    #pragma unroll
    for (int c = 0; c < 8; ++c) {
        f16x8 w;
        #pragma unroll
        for (int j = 0; j < 8; ++j) w[j] = (f16)vv[8 * c + j];
        *(f16x8*)&dst[8 * c] = w;
    }
    atomicAdd(&stats[t], s);
    atomicAdd(&stats[256 + t], ss);
}

// ---------------------------------------------------------------------------
// Kernel E: out = gamma*(y-mean)*rstd + beta, f16 y -> f32 out.
// grid 1024 = (b, o); 256 threads, 16 elems each.
// ---------------------------------------------------------------------------
__global__ __launch_bounds__(256) void k_bnapply(const f16* __restrict__ y,
                                                 const float* __restrict__ stats,
                                                 const float* __restrict__ gamma,
                                                 const float* __restrict__ beta,
                                                 float* __restrict__ out) {
    int b = blockIdx.x >> 8;
    int o = blockIdx.x & 255;
    int t = threadIdx.x;
    float mean = stats[o] * (1.0f / 16384.0f);
    float var = stats[256 + o] * (1.0f / 16384.0f) - mean * mean;
    float rstd = rsqrtf(var + 1e-5f);
    float g = gamma[o] * rstd;
    float bt = beta[o] - mean * g;
    const f16* src = y + ((size_t)(b * OUT_ + o)) * N_ + t * 16;
    float* dst = out + ((size_t)(b * OUT_ + o)) * N_ + t * 16;
    #pragma unroll
    for (int i = 0; i < 2; ++i) {
        f16x8 v = *(const f16x8*)&src[i * 8];
        float4 a, c;
        a.x = (float)v[0] * g + bt;
        a.y = (float)v[1] * g + bt;
        a.z = (float)v[2] * g + bt;
        a.w = (float)v[3] * g + bt;
        c.x = (float)v[4] * g + bt;
        c.y = (float)v[5] * g + bt;
        c.z = (float)v[6] * g + bt;
        c.w = (float)v[7] * g + bt;
        *(float4*)&dst[i * 8] = a;
        *(float4*)&dst[i * 8 + 4] = c;
    }
}

extern "C" void kernel_launch(void* const* d_in, const int* in_sizes, int n_in,
                              void* d_out, int out_size, void* d_ws, size_t ws_size,
                              hipStream_t stream) {
    const float* x     = (const float*)d_in[0];
    const float* W     = (const float*)d_in[1];
    const float* gamma = (const float*)d_in[2];
    const float* beta  = (const float*)d_in[3];
    float* out = (float*)d_out;

    f16* xt    = (f16*)d_ws;                      // 8 MB (reused as y by merge)
    f16* supT  = xt + (size_t)B_ * N_ * C_;       // 8 MB
    f16* Wt    = supT + (size_t)B_ * N_ * OUT_;   // 128 KB
    f16* Op    = Wt + C_ * OUT_;                  // 512*32KB = 16.8 MB
    float* Ml  = (float*)(Op + (size_t)512 * 64 * 256);  // 256 KB
    float* stats = Ml + 512 * 128;                // 2 KB
    f16* y     = xt;                              // alias: xt dead after flash

    k_prep<<<1089, 256, 0, stream>>>(x, W, xt, Wt, stats);
    k_support<<<1024, 256, 0, stream>>>(xt, Wt, supT);
    k_flash<<<512, 256, 0, stream>>>(xt, supT, Op, Ml);
    k_merge<<<256, 256, 0, stream>>>(Op, Ml, y, stats);
    k_bnapply<<<1024, 256, 0, stream>>>(y, stats, gamma, beta, out);
}

// Round 5
// 345.259 us; speedup vs baseline: 1.2632x; 1.2632x over previous
//
#include <hip/hip_runtime.h>

typedef _Float16 f16;
typedef _Float16 f16x8 __attribute__((ext_vector_type(8)));
typedef float f32x4 __attribute__((ext_vector_type(4)));

#define B_   4
#define C_   256
#define N_   4096
#define OUT_ 256

// ---------------------------------------------------------------------------
// Kernel A: transpose+convert x [B,C,N] f32 -> xt [B,N,C] f16, W -> Wt[o][c] f16,
// and zero the BN-stats accumulators (block 1088).
// ---------------------------------------------------------------------------
__global__ __launch_bounds__(256) void k_prep(const float* __restrict__ x,
                                              const float* __restrict__ W,
                                              f16* __restrict__ xt,
                                              f16* __restrict__ Wt,
                                              float* __restrict__ stats) {
    int bid = blockIdx.x;
    int t = threadIdx.x;
    if (bid < 1024) {
        int b  = bid >> 8;
        int ct = (bid >> 6) & 3;
        int nt = bid & 63;
        int c0 = ct * 64, n0 = nt * 64;
        __shared__ float tile[64][65];
        int nl = t & 63;
        int r0 = t >> 6;
        #pragma unroll
        for (int i = 0; i < 16; ++i) {
            int cl = i * 4 + r0;
            tile[cl][nl] = x[((b * C_ + c0 + cl) * N_) + n0 + nl];
        }
        __syncthreads();
        #pragma unroll
        for (int i = 0; i < 16; ++i) {
            int nl2 = i * 4 + r0;
            int cl2 = nl;
            xt[((b * N_ + n0 + nl2) * C_) + c0 + cl2] = (f16)tile[cl2][nl2];
        }
    } else if (bid < 1088) {
        int wb = bid - 1024;
        #pragma unroll
        for (int i = 0; i < 4; ++i) {
            int idx = wb * 1024 + i * 256 + t;
            int c = idx >> 8, o = idx & 255;
            Wt[o * C_ + c] = (f16)W[idx];
        }
    } else {
        if (t < 512) stats[t] = 0.f;
    }
}

// ---------------------------------------------------------------------------
// Kernel B: support^T[b][o][m] = sum_c xt[b][m][c] * W[c][o]   (f16 out)
// ---------------------------------------------------------------------------
__global__ __launch_bounds__(256) void k_support(const f16* __restrict__ xt,
                                                 const f16* __restrict__ Wt,
                                                 f16* __restrict__ supT) {
    int bid = blockIdx.x;
    int b  = bid >> 8;
    int ot = (bid >> 6) & 3;
    int mt = bid & 63;
    int o0 = ot * 64, m0 = mt * 64;
    __shared__ __align__(16) f16 Ws[64][264];
    __shared__ __align__(16) f16 Xs[64][264];
    int t = threadIdx.x;
    int wave = t >> 6, lane = t & 63, q = lane >> 4, l15 = lane & 15;
    #pragma unroll
    for (int p = 0; p < 8; ++p) {
        int idx = p * 256 + t;
        int row = idx >> 5, ch = (idx & 31) * 8;
        *(uint4*)&Ws[row][ch] = *(const uint4*)&Wt[(o0 + row) * C_ + ch];
        *(uint4*)&Xs[row][ch] = *(const uint4*)&xt[((b * N_) + m0 + row) * C_ + ch];
    }
    __syncthreads();
    f32x4 acc[4] = {};
    #pragma unroll
    for (int kk = 0; kk < 8; ++kk) {
        f16x8 a = *(f16x8*)&Ws[16 * wave + l15][kk * 32 + q * 8];
        #pragma unroll
        for (int ct = 0; ct < 4; ++ct) {
            f16x8 bb = *(f16x8*)&Xs[16 * ct + l15][kk * 32 + q * 8];
            acc[ct] = __builtin_amdgcn_mfma_f32_16x16x32_f16(a, bb, acc[ct], 0, 0, 0);
        }
    }
    #pragma unroll
    for (int ct = 0; ct < 4; ++ct)
        #pragma unroll
        for (int r = 0; r < 4; ++r) {
            int og = o0 + 16 * wave + q * 4 + r;
            int mg = m0 + 16 * ct + l15;
            supT[((b * OUT_ + og) * N_) + mg] = (f16)acc[ct][r];
        }
}

// ---------------------------------------------------------------------------
// Kernel C: split-K(2) flash, S^T formulation. grid 512: bid = h*256 + b*64 + nb.
// Waves partition the m-rows of each K-tile (A-frags, 8KB/wave-iter);
// Q (all 64 n) lives in registers as B-frags (128 VGPRs, loaded once).
// Softmax: per-wave partial max -> PM exchange -> global alpha; l kept
// per-wave-partial, summed once at the end. P round-trips LDS for PV.
// ---------------------------------------------------------------------------
__global__ __launch_bounds__(256, 2) void k_flash(const f16* __restrict__ xt,
                                                  const f16* __restrict__ supT,
                                                  f16* __restrict__ Op,
                                                  float* __restrict__ Ml) {
    int bid = blockIdx.x;
    int h  = bid >> 8;
    int b  = (bid >> 6) & 3;
    int n0 = (bid & 63) * 64;

    __shared__ __align__(16) f16 Ks[64][260];   // 33280 B
    __shared__ __align__(16) f16 Vt[256][68];   // 34816 B
    __shared__ __align__(16) f16 Ps[64][68];    //  8704 B
    __shared__ __align__(16) float PM[64][4];   //  1024 B
    __shared__ __align__(16) float Al[64];      //   256 B  (total ~78.3 KB -> 2 blk/CU)

    int t = threadIdx.x;
    int wave = t >> 6, lane = t & 63, q = lane >> 4, l15 = lane & 15;

    // Q as B-fragments for all 4 n-tiles: qf[ct][kk], n = 16*ct + l15
    const f16* qbase = xt + ((size_t)(b * N_) + n0 + l15) * C_ + q * 8;
    f16x8 qf[4][8];
    #pragma unroll
    for (int ct = 0; ct < 4; ++ct)
        #pragma unroll
        for (int kk = 0; kk < 8; ++kk)
            qf[ct][kk] = *(const f16x8*)&qbase[(size_t)ct * 16 * C_ + kk * 32];

    f32x4 oacc[4][4] = {};      // [nt][ot]
    float m_run[4], l_run[4];   // indexed by ct: n = 16*ct + l15; l_run is per-wave partial
    #pragma unroll
    for (int r = 0; r < 4; ++r) { m_run[r] = -1e30f; l_run[r] = 0.f; }

    for (int it = 0; it < 32; ++it) {
        int m0 = h * 2048 + it * 64;
        // stage K (64x256) and V^T (256x64)
        #pragma unroll
        for (int p = 0; p < 8; ++p) {
            int idx = p * 256 + t;
            int row = idx >> 5, ch = (idx & 31) * 8;
            *(uint4*)&Ks[row][ch] = *(const uint4*)&xt[((b * N_) + m0 + row) * C_ + ch];
        }
        #pragma unroll
        for (int p = 0; p < 8; ++p) {
            int idx = p * 256 + t;
            int o = idx >> 3, j8 = (idx & 7) * 8;
            *(uint4*)&Vt[o][j8] = *(const uint4*)&supT[((b * OUT_ + o) * N_) + m0 + j8];
        }
        __syncthreads();   // (A) staging visible

        // S^T = K Q^T: rows m (wave's 16), cols n (all 64)
        f32x4 sacc[4] = {};
        #pragma unroll
        for (int kk = 0; kk < 8; ++kk) {
            f16x8 kf = *(f16x8*)&Ks[16 * wave + l15][kk * 32 + q * 8];
            #pragma unroll
            for (int ct = 0; ct < 4; ++ct)
                sacc[ct] = __builtin_amdgcn_mfma_f32_16x16x32_f16(kf, qf[ct][kk], sacc[ct], 0, 0, 0);
        }
        // per-wave partial max over its 16 m (regs + quads), publish to PM
        #pragma unroll
        for (int ct = 0; ct < 4; ++ct) {
            float mx = fmaxf(fmaxf(sacc[ct][0], sacc[ct][1]), fmaxf(sacc[ct][2], sacc[ct][3]));
            mx = fmaxf(mx, __shfl_xor(mx, 16));
            mx = fmaxf(mx, __shfl_xor(mx, 32));
            if (q == 0) PM[16 * ct + l15][wave] = mx;
        }
        __syncthreads();   // (B) PM visible

        float alpha[4];
        #pragma unroll
        for (int ct = 0; ct < 4; ++ct) {
            float4 pm4 = *(const float4*)&PM[16 * ct + l15][0];
            float mx = fmaxf(fmaxf(pm4.x, pm4.y), fmaxf(pm4.z, pm4.w));
            float mnew = fmaxf(m_run[ct], mx);
            alpha[ct] = __expf(m_run[ct] - mnew);
            m_run[ct] = mnew;
            float p0 = __expf(sacc[ct][0] - mnew);
            float p1 = __expf(sacc[ct][1] - mnew);
            float p2 = __expf(sacc[ct][2] - mnew);
            float p3 = __expf(sacc[ct][3] - mnew);
            int n = 16 * ct + l15;
            int mloc = 16 * wave + 4 * q;
            Ps[n][mloc + 0] = (f16)p0;
            Ps[n][mloc + 1] = (f16)p1;
            Ps[n][mloc + 2] = (f16)p2;
            Ps[n][mloc + 3] = (f16)p3;
            float sum = p0 + p1 + p2 + p3;
            sum += __shfl_xor(sum, 16);
            sum += __shfl_xor(sum, 32);
            l_run[ct] = l_run[ct] * alpha[ct] + sum;
        }
        if (wave == 0 && q == 0) {
            #pragma unroll
            for (int ct = 0; ct < 4; ++ct) Al[16 * ct + l15] = alpha[ct];
        }
        __syncthreads();   // (C) Ps/Al visible

        // rescale O by alpha (rows n = 16nt + 4q + r), then O += P V
        float4 av[4];
        #pragma unroll
        for (int nt = 0; nt < 4; ++nt)
            av[nt] = *(const float4*)&Al[16 * nt + 4 * q];
        #pragma unroll
        for (int nt = 0; nt < 4; ++nt)
            #pragma unroll
            for (int ot = 0; ot < 4; ++ot)
                #pragma unroll
                for (int r = 0; r < 4; ++r)
                    oacc[nt][ot][r] *= ((const float*)&av[nt])[r];
        #pragma unroll
        for (int ks = 0; ks < 2; ++ks) {
            f16x8 bf[4];
            #pragma unroll
            for (int ot = 0; ot < 4; ++ot)
                bf[ot] = *(f16x8*)&Vt[64 * wave + 16 * ot + l15][ks * 32 + q * 8];
            #pragma unroll
            for (int nt = 0; nt < 4; ++nt) {
                f16x8 af = *(f16x8*)&Ps[16 * nt + l15][ks * 32 + q * 8];
                #pragma unroll
                for (int ot = 0; ot < 4; ++ot)
                    oacc[nt][ot] = __builtin_amdgcn_mfma_f32_16x16x32_f16(af, bf[ot], oacc[nt][ot], 0, 0, 0);
            }
        }
        __syncthreads();   // (D) guard before next staging overwrites Ks/Vt
    }

    // finalize: l_total = sum of per-wave partials (reuse PM)
    if (q == 0) {
        #pragma unroll
        for (int ct = 0; ct < 4; ++ct) PM[16 * ct + l15][wave] = l_run[ct];
    }
    __syncthreads();
    if (t < 64) {
        float4 p4 = *(const float4*)&PM[t][0];
        float lt = p4.x + p4.y + p4.z + p4.w;
        Al[t] = 1.0f / lt;
        float* Mlb = Ml + (size_t)bid * 128;
        Mlb[t] = m_run[t >> 4];     // wave-0 lane t holds global m for n = t
        Mlb[64 + t] = lt;
    }
    __syncthreads();
    float4 lv[4];
    #pragma unroll
    for (int nt = 0; nt < 4; ++nt)
        lv[nt] = *(const float4*)&Al[16 * nt + 4 * q];

    f16* Obase = Op + (size_t)bid * (64 * 256);
    #pragma unroll
    for (int nt = 0; nt < 4; ++nt)
        #pragma unroll
        for (int ot = 0; ot < 4; ++ot)
            #pragma unroll
            for (int r = 0; r < 4; ++r) {
                int n = 16 * nt + q * 4 + r;
                int o = 64 * wave + 16 * ot + l15;
                Obase[n * 256 + o] = (f16)(oacc[nt][ot][r] * ((const float*)&lv[nt])[r]);
            }
}

// ---------------------------------------------------------------------------
// Kernel C2: merge 2 split-K halves + LeakyReLU -> y (f16, [b][o][n]),
// and accumulate per-channel BN sums via atomics.
// ---------------------------------------------------------------------------
__global__ __launch_bounds__(256) void k_merge(const f16* __restrict__ Op,
                                               const float* __restrict__ Ml,
                                               f16* __restrict__ y,
                                               float* __restrict__ stats) {
    int bid = blockIdx.x;
    int b  = bid >> 6;
    int nb = bid & 63;
    int t = threadIdx.x;
    const f16* O0 = Op + (size_t)bid * (64 * 256);
    const f16* O1 = Op + (size_t)(bid + 256) * (64 * 256);
    __shared__ float cs[2][64];
    if (t < 64) {
        const float* M0 = Ml + (size_t)bid * 128;
        const float* M1 = Ml + (size_t)(bid + 256) * 128;
        float m0 = M0[t], l0 = M0[64 + t];
        float m1 = M1[t], l1 = M1[64 + t];
        float M = fmaxf(m0, m1);
        float w0 = __expf(m0 - M) * l0;
        float w1 = __expf(m1 - M) * l1;
        float inv = 1.0f / (w0 + w1);
        cs[0][t] = w0 * inv;
        cs[1][t] = w1 * inv;
    }
    __syncthreads();
    float vv[64];
    float s = 0.f, ss = 0.f;
    #pragma unroll
    for (int n = 0; n < 64; ++n) {
        float v = cs[0][n] * (float)O0[n * 256 + t] + cs[1][n] * (float)O1[n * 256 + t];
        v = v >= 0.f ? v : 0.01f * v;
        vv[n] = v;
        s += v;
        ss += v * v;
    }
    f16* dst = y + ((size_t)(b * OUT_ + t)) * N_ + nb * 64;
    #pragma unroll
    for (int c = 0; c < 8; ++c) {
        f16x8 w;
        #pragma unroll
        for (int j = 0; j < 8; ++j) w[j] = (f16)vv[8 * c + j];
        *(f16x8*)&dst[8 * c] = w;
    }
    atomicAdd(&stats[t], s);
    atomicAdd(&stats[256 + t], ss);
}

// ---------------------------------------------------------------------------
// Kernel E: out = gamma*(y-mean)*rstd + beta, f16 y -> f32 out.
// ---------------------------------------------------------------------------
__global__ __launch_bounds__(256) void k_bnapply(const f16* __restrict__ y,
                                                 const float* __restrict__ stats,
                                                 const float* __restrict__ gamma,
                                                 const float* __restrict__ beta,
                                                 float* __restrict__ out) {
    int b = blockIdx.x >> 8;
    int o = blockIdx.x & 255;
    int t = threadIdx.x;
    float mean = stats[o] * (1.0f / 16384.0f);
    float var = stats[256 + o] * (1.0f / 16384.0f) - mean * mean;
    float rstd = rsqrtf(var + 1e-5f);
    float g = gamma[o] * rstd;
    float bt = beta[o] - mean * g;
    const f16* src = y + ((size_t)(b * OUT_ + o)) * N_ + t * 16;
    float* dst = out + ((size_t)(b * OUT_ + o)) * N_ + t * 16;
    #pragma unroll
    for (int i = 0; i < 2; ++i) {
        f16x8 v = *(const f16x8*)&src[i * 8];
        float4 a, c;
        a.x = (float)v[0] * g + bt;
        a.y = (float)v[1] * g + bt;
        a.z = (float)v[2] * g + bt;
        a.w = (float)v[3] * g + bt;
        c.x = (float)v[4] * g + bt;
        c.y = (float)v[5] * g + bt;
        c.z = (float)v[6] * g + bt;
        c.w = (float)v[7] * g + bt;
        *(float4*)&dst[i * 8] = a;
        *(float4*)&dst[i * 8 + 4] = c;
    }
}

extern "C" void kernel_launch(void* const* d_in, const int* in_sizes, int n_in,
                              void* d_out, int out_size, void* d_ws, size_t ws_size,
                              hipStream_t stream) {
    const float* x     = (const float*)d_in[0];
    const float* W     = (const float*)d_in[1];
    const float* gamma = (const float*)d_in[2];
    const float* beta  = (const float*)d_in[3];
    float* out = (float*)d_out;

    f16* xt    = (f16*)d_ws;                      // 8 MB (reused as y by merge)
    f16* supT  = xt + (size_t)B_ * N_ * C_;       // 8 MB
    f16* Wt    = supT + (size_t)B_ * N_ * OUT_;   // 128 KB
    f16* Op    = Wt + C_ * OUT_;                  // 512*32KB = 16.8 MB
    float* Ml  = (float*)(Op + (size_t)512 * 64 * 256);  // 256 KB
    float* stats = Ml + 512 * 128;                // 2 KB
    f16* y     = xt;                              // alias: xt dead after flash

    k_prep<<<1089, 256, 0, stream>>>(x, W, xt, Wt, stats);
    k_support<<<1024, 256, 0, stream>>>(xt, Wt, supT);
    k_flash<<<512, 256, 0, stream>>>(xt, supT, Op, Ml);
    k_merge<<<256, 256, 0, stream>>>(Op, Ml, y, stats);
    k_bnapply<<<1024, 256, 0, stream>>>(y, stats, gamma, beta, out);
}